// Round 10
// baseline (133.115 us; speedup 1.0000x reference)
//
#include <hip/hip_runtime.h>
#include <hip/hip_bf16.h>

typedef __bf16 bf16_t;
typedef __bf16 bf16x8 __attribute__((ext_vector_type(8)));
typedef float  f32x4  __attribute__((ext_vector_type(4)));
typedef float  f32x16 __attribute__((ext_vector_type(16)));

#define MFMA32(a, b, c) __builtin_amdgcn_mfma_f32_32x32x16_bf16((a), (b), (c), 0, 0, 0)

constexpr int Bc = 4, Lc = 2048, Hc = 8, Dc = 64;
constexpr int HD = Hc * Dc;            // 512
constexpr int TRAINc = 1536;
constexpr int ROWS_BLK = 128;          // q rows per workgroup (4 waves x 32)
constexpr int KT = 64;                 // keys per k-tile

constexpr int PREPK_BLOCKS = (int)((size_t)Bc * Lc * Hc * Dc / 8 / 256);  // 2048

// ---------------- fused prep: K cast + V transpose in one launch ----------------
__global__ void prep_fused(const float* __restrict__ K, bf16_t* __restrict__ Kb,
                           const float* __restrict__ V, bf16_t* __restrict__ Vt) {
  __shared__ bf16_t T[64][64];
  const int t = (int)threadIdx.x;

  if ((int)blockIdx.x < PREPK_BLOCKS) {
    size_t g = ((size_t)blockIdx.x * 256 + t) * 8;
    float4 a = *(const float4*)(K + g);
    float4 b = *(const float4*)(K + g + 4);
    bf16x8 v;
    v[0] = (bf16_t)a.x; v[1] = (bf16_t)a.y; v[2] = (bf16_t)a.z; v[3] = (bf16_t)a.w;
    v[4] = (bf16_t)b.x; v[5] = (bf16_t)b.y; v[6] = (bf16_t)b.z; v[7] = (bf16_t)b.w;
    *(bf16x8*)(Kb + g) = v;
    return;
  }

  const int bid = (int)blockIdx.x - PREPK_BLOCKS;
  const int kt = bid & 31, h = (bid >> 5) & 7, b = bid >> 8;
  {
    int kl = t >> 2, dp = (t & 3) << 4;
    const float* s = V + ((size_t)(b * Lc + kt * 64 + kl) * Hc + h) * Dc + dp;
    bf16x8 v0, v1;
    float4 f;
    f = *(const float4*)(s);      v0[0]=(bf16_t)f.x; v0[1]=(bf16_t)f.y; v0[2]=(bf16_t)f.z; v0[3]=(bf16_t)f.w;
    f = *(const float4*)(s + 4);  v0[4]=(bf16_t)f.x; v0[5]=(bf16_t)f.y; v0[6]=(bf16_t)f.z; v0[7]=(bf16_t)f.w;
    f = *(const float4*)(s + 8);  v1[0]=(bf16_t)f.x; v1[1]=(bf16_t)f.y; v1[2]=(bf16_t)f.z; v1[3]=(bf16_t)f.w;
    f = *(const float4*)(s + 12); v1[4]=(bf16_t)f.x; v1[5]=(bf16_t)f.y; v1[6]=(bf16_t)f.z; v1[7]=(bf16_t)f.w;
    const int x = kl >> 3;
    const int c0 = dp >> 3;
    *(bf16x8*)&T[kl][(c0 ^ x) << 3]       = v0;
    *(bf16x8*)&T[kl][((c0 + 1) ^ x) << 3] = v1;
  }
  __syncthreads();
  {
    int d = t >> 2, kp = (t & 3) << 4;
    const int xa = kp >> 3;
    const int xb = xa + 1;
    const int lo = d & 7, hi = d >> 3;
    const int x0 = ((hi ^ xa) << 3) + lo;
    const int x1 = ((hi ^ xb) << 3) + lo;
    bf16x8 o0, o1;
#pragma unroll
    for (int i = 0; i < 8; ++i) { o0[i] = T[kp + i][x0]; o1[i] = T[kp + 8 + i][x1]; }
    bf16_t* dst = Vt + ((size_t)((b * Hc + h) * Dc + d)) * Lc + kt * 64 + kp;
    *(bf16x8*)dst = o0;
    *(bf16x8*)(dst + 8) = o1;
  }
}

// ---------------- main attention ----------------
static __device__ __forceinline__ void load16(const bf16_t* g, bf16_t* l) {
  __builtin_amdgcn_global_load_lds(
      (const __attribute__((address_space(1))) unsigned int*)g,
      (__attribute__((address_space(3))) unsigned int*)l, 16, 0, 0);
}

static __device__ __forceinline__ bf16x8 mk8(unsigned w0, unsigned w1,
                                             unsigned w2, unsigned w3) {
  union { unsigned u[4]; bf16x8 v; } x;
  x.u[0] = w0; x.u[1] = w1; x.u[2] = w2; x.u[3] = w3;
  return x.v;
}

// 32x32x16 MFMA, 32 q-rows per wave (4 waves = 128 rows/block): halves MFMA
// issues, ds_reads, and addressing per q.k pair vs the 16x16 version; softmax
// stays fully in-register (swapped QK^T; one permlane32_swap per dword pair).
// S^T lane layout: lane(hi=l>>5, lq=l&31) holds S[key=(c&3)+8(c>>2)+4hi][q=lq].
__global__ __launch_bounds__(256, 2)
void continual_attn(const float* __restrict__ Qg, const bf16_t* __restrict__ Kb,
                    const bf16_t* __restrict__ Vt, const int* __restrict__ ATT,
                    float* __restrict__ OUT)
{
  // [key][64] / [d][64] rows of 128B; 16B slot s of row r holds logical chunk s^(r&7)
  __shared__ __align__(16) bf16_t Klds[2][KT * 64];   // 2 x 8 KB
  __shared__ __align__(16) bf16_t Vlds[2][Dc * KT];   // 2 x 8 KB  (total 32 KB)

  const int bid  = blockIdx.x;
  // heavy-light pairing over 512 blocks: CU sees (15-g) and (g) -> 27..34 tiles
  const int g    = bid >> 5;
  const int qblk = (g < 8) ? (15 - g) : (g - 8);
  const int h    = bid & 7;
  const int b    = (bid >> 3) & 3;
  const int q0   = qblk * ROWS_BLK;

  const int tid  = (int)threadIdx.x;
  const int wave = tid >> 6;
  const int lane = tid & 63;
  const int hi   = lane >> 5;          // half-wave
  const int lq   = lane & 31;          // this lane's q (and d) index
  const int qw   = q0 + wave * 32;
  const int qi   = qw + lq;            // this lane's q-row

  const size_t bhQ = (size_t)b * Lc * HD + (size_t)h * Dc;

  // staging source pointers (per-lane; k-offset added per tile). XOR swizzle on source.
  const int kr = tid >> 3;                                   // row 0..31
  const bf16_t* ksrcA = Kb + bhQ + (size_t)kr * HD + (((tid & 7) ^ (kr & 7)) << 3);
  const bf16_t* vsrcA = Vt + ((size_t)((b * Hc + h) * Dc + kr)) * Lc + (((tid & 7) ^ (kr & 7)) << 3);
  const bf16_t* vsrcB = vsrcA + (size_t)32 * Lc;             // d rows 32..63, same swizzle

  // ---- Q B-fragments: bq[s] = Q[q=qi][d=16s+8hi+j], prescaled by 1/8*log2(e) ----
  bf16x8 bq[4];
  {
    const float* qp = Qg + bhQ + (size_t)qi * HD + 8 * hi;
    const float SC = 0.125f * 1.44269504f;
#pragma unroll
    for (int s = 0; s < 4; ++s) {
      float4 lo = *(const float4*)(qp + 16 * s);
      float4 h4 = *(const float4*)(qp + 16 * s + 4);
      bf16x8 v;
      v[0] = (bf16_t)(lo.x * SC); v[1] = (bf16_t)(lo.y * SC);
      v[2] = (bf16_t)(lo.z * SC); v[3] = (bf16_t)(lo.w * SC);
      v[4] = (bf16_t)(h4.x * SC); v[5] = (bf16_t)(h4.y * SC);
      v[6] = (bf16_t)(h4.z * SC); v[7] = (bf16_t)(h4.w * SC);
      bq[s] = v;
    }
  }

  // ---- per-lane mask scalars ----
  const bool testblk = (q0 >= TRAINc);
  int kendL, cstartL;
  if (testblk) {
    kendL   = ATT[b * 64 + ((qi - TRAINc) >> 3)] + 1;
    cstartL = qi & ~7;
  } else {
    kendL   = qi + 1;
    cstartL = 0;
  }

  int ntA, ndiag, kfull_end;
  if (testblk) {
    int c0 = (q0 - TRAINc) >> 3;      // 16 chunks per 128-row block
    int amax = 0, amin = 0x7fffffff;
#pragma unroll
    for (int i = 0; i < 16; ++i) {
      int a = ATT[b * 64 + c0 + i];
      amax = (a > amax) ? a : amax;
      amin = (a < amin) ? a : amin;
    }
    ntA = (amax >> 6) + 1;   // 64-wide tiles covering [0, amax]
    ndiag = 2;               // two 64-wide diagonal tiles at k0 = q0, q0+64
    kfull_end = amin + 1;
  } else {
    ntA = 2 * qblk + 2;      // causal tiles covering [0, q0+128)
    ndiag = 0;
    kfull_end = q0 + 1;
  }
  const int ntot = ntA + ndiag;

  float ls[4] = {0.f, 0.f, 0.f, 0.f};
  f32x16 o0 = {0,0,0,0,0,0,0,0,0,0,0,0,0,0,0,0};
  f32x16 o1 = {0,0,0,0,0,0,0,0,0,0,0,0,0,0,0,0};

  const int swz = lq & 7;              // row-XOR for this lane's LDS rows

  // prologue: stage tile 0 into buf 0 (tile 0 always k0=0)
  {
    load16(ksrcA, Klds[0] + wave * 512);
    load16(ksrcA + (size_t)32 * HD, Klds[0] + 2048 + wave * 512);
    load16(vsrcA, Vlds[0] + wave * 512);
    load16(vsrcB, Vlds[0] + 2048 + wave * 512);
  }

  for (int ti = 0; ti < ntot; ++ti) {
    const int buf = ti & 1;
    __syncthreads();   // drains vmcnt -> buf[ti&1] ready; prior reads of other buf done

    if (ti + 1 < ntot) {   // prefetch next tile
      const int kn = (ti + 1 < ntA) ? (ti + 1) * KT : q0 + (ti + 1 - ntA) * KT;
      bf16_t* kd = Klds[1 - buf];
      bf16_t* vd = Vlds[1 - buf];
      load16(ksrcA + (size_t)kn * HD, kd + wave * 512);
      load16(ksrcA + (size_t)(kn + 32) * HD, kd + 2048 + wave * 512);
      load16(vsrcA + kn, vd + wave * 512);
      load16(vsrcB + kn, vd + 2048 + wave * 512);
    }

    const bf16_t* kb = Klds[buf];
    const bf16_t* vbuf = Vlds[buf];
    const int k0 = (ti < ntA) ? ti * KT : q0 + (ti - ntA) * KT;

    // ---- S^T = K Q^T: two 32x32 tiles (keys k0..+31, k0+32..+63) ----
    f32x16 s0 = {0,0,0,0,0,0,0,0,0,0,0,0,0,0,0,0};
    f32x16 s1 = {0,0,0,0,0,0,0,0,0,0,0,0,0,0,0,0};
    __builtin_amdgcn_s_setprio(1);
#pragma unroll
    for (int s = 0; s < 4; ++s) {     // K-dim d = 16s..16s+15
      const int sl = ((2 * s + hi) ^ swz) << 3;
      bf16x8 ka0 = *(const bf16x8*)(kb + lq * 64 + sl);
      bf16x8 ka1 = *(const bf16x8*)(kb + (lq + 32) * 64 + sl);
      s0 = MFMA32(ka0, bq[s], s0);
      s1 = MFMA32(ka1, bq[s], s1);
    }
    __builtin_amdgcn_s_setprio(0);

    // ---- mask (key for reg c of tile T: k0 + 32T + (c&3)+8*(c>>2)+4*hi) ----
    const int mode = (ti >= ntA) ? 2 : ((k0 + KT <= kfull_end) ? 0 : 1);
    if (mode == 1) {
#pragma unroll
      for (int c = 0; c < 16; ++c) {
        const int kv = k0 + (c & 3) + 8 * (c >> 2) + 4 * hi;
        if (kv >= kendL)      s0[c] = -1e30f;
        if (kv + 32 >= kendL) s1[c] = -1e30f;
      }
    } else if (mode == 2) {
#pragma unroll
      for (int c = 0; c < 16; ++c) {
        const int kv = k0 + (c & 3) + 8 * (c >> 2) + 4 * hi;
        if (kv < cstartL || kv > qi)           s0[c] = -1e30f;
        if (kv + 32 < cstartL || kv + 32 > qi) s1[c] = -1e30f;
      }
    }

    // ---- exp2 (fixed-max: bounded logits, fp32/bf16-safe) ----
    float p0[16], p1[16];
#pragma unroll
    for (int c = 0; c < 16; ++c) {
      p0[c] = __builtin_amdgcn_exp2f(s0[c]);
      p1[c] = __builtin_amdgcn_exp2f(s1[c]);
      ls[c & 3] += p0[c] + p1[c];
    }

    // ---- pack pairs; one permlane32_swap per dword pair builds A-frags ----
    // D[j] = keys (2j',2j'+1)-pattern; swap32(Dj, Dj+2) -> slots (j&1, j&1+2)
    unsigned D0[8], D1[8];
#pragma unroll
    for (int j = 0; j < 8; ++j) {
      asm("v_cvt_pk_bf16_f32 %0, %1, %2" : "=v"(D0[j]) : "v"(p0[2*j]), "v"(p0[2*j+1]));
      asm("v_cvt_pk_bf16_f32 %0, %1, %2" : "=v"(D1[j]) : "v"(p1[2*j]), "v"(p1[2*j+1]));
    }
#pragma unroll
    for (int j = 0; j < 2; ++j) {     // tile0: k-steps (keys 0-15, 16-31)
      asm volatile("v_permlane32_swap_b32 %0, %1" : "+v"(D0[4*j]),   "+v"(D0[4*j+2]));
      asm volatile("v_permlane32_swap_b32 %0, %1" : "+v"(D0[4*j+1]), "+v"(D0[4*j+3]));
      asm volatile("v_permlane32_swap_b32 %0, %1" : "+v"(D1[4*j]),   "+v"(D1[4*j+2]));
      asm volatile("v_permlane32_swap_b32 %0, %1" : "+v"(D1[4*j+1]), "+v"(D1[4*j+3]));
    }
    bf16x8 pA[4];
    pA[0] = mk8(D0[0], D0[1], D0[2], D0[3]);   // keys k0+ 0..15
    pA[1] = mk8(D0[4], D0[5], D0[6], D0[7]);   // keys k0+16..31
    pA[2] = mk8(D1[0], D1[1], D1[2], D1[3]);   // keys k0+32..47
    pA[3] = mk8(D1[4], D1[5], D1[6], D1[7]);   // keys k0+48..63

    // ---- O += P V  (2 d-tiles x 4 k-steps) ----
    __builtin_amdgcn_s_setprio(1);
#pragma unroll
    for (int t = 0; t < 4; ++t) {     // keys 16t..16t+15
      const int sl = ((2 * t + hi) ^ swz) << 3;
      bf16x8 v0 = *(const bf16x8*)(vbuf + lq * 64 + sl);
      bf16x8 v1 = *(const bf16x8*)(vbuf + (lq + 32) * 64 + sl);
      o0 = MFMA32(pA[t], v0, o0);
      o1 = MFMA32(pA[t], v1, o1);
    }
    __builtin_amdgcn_s_setprio(0);
  }

  // ---- epilogue ----
  float rs = (ls[0] + ls[1]) + (ls[2] + ls[3]);
  rs += __shfl_xor(rs, 32);           // both halves hold full denom for q = qw+lq

#pragma unroll
  for (int c = 0; c < 16; ++c) {
    const int qlocal = (c & 3) + 8 * (c >> 2) + 4 * hi;
    float dr = __shfl(rs, qlocal);    // lane qlocal holds denom of q = qw+qlocal
    float inv = 1.f / dr;
    float* op = OUT + ((size_t)b * Lc + (qw + qlocal)) * HD + (size_t)h * Dc + lq;
    op[0]  = o0[c] * inv;
    op[32] = o1[c] * inv;
  }
}

extern "C" void kernel_launch(void* const* d_in, const int* in_sizes, int n_in,
                              void* d_out, int out_size, void* d_ws, size_t ws_size,
                              hipStream_t stream) {
  const float* Q   = (const float*)d_in[0];
  const float* K   = (const float*)d_in[1];
  const float* V   = (const float*)d_in[2];
  const int*   ATT = (const int*)d_in[3];
  float* OUT = (float*)d_out;
  (void)in_sizes; (void)n_in; (void)out_size; (void)ws_size;

  const size_t NE = (size_t)Bc * Lc * Hc * Dc;
  bf16_t* Kb = (bf16_t*)d_ws;
  bf16_t* Vt = Kb + NE;

  prep_fused<<<dim3((unsigned)(PREPK_BLOCKS + Bc * Hc * (Lc / 64))), dim3(256), 0, stream>>>(K, Kb, V, Vt);
  continual_attn<<<dim3(Bc * Hc * (Lc / ROWS_BLK)), dim3(256), 0, stream>>>(Q, Kb, Vt, ATT, OUT);
}

// Round 11
// 123.631 us; speedup vs baseline: 1.0767x; 1.0767x over previous
//
#include <hip/hip_runtime.h>
#include <hip/hip_bf16.h>

typedef __bf16 bf16_t;
typedef __bf16 bf16x8 __attribute__((ext_vector_type(8)));
typedef float  f32x4  __attribute__((ext_vector_type(4)));

#define MFMA16(a, b, c) __builtin_amdgcn_mfma_f32_16x16x32_bf16((a), (b), (c), 0, 0, 0)

constexpr int Bc = 4, Lc = 2048, Hc = 8, Dc = 64;
constexpr int HD = Hc * Dc;            // 512
constexpr int TRAINc = 1536;
constexpr int ROWS_BLK = 64;           // q rows per workgroup (4 waves x 16)
constexpr int KT = 64;                 // keys per k-tile

// Single kernel: NO prep pass. K/V are read as fp32 straight from the inputs;
// each block casts+transposes its own tiles inline (global->reg->cvt->LDS in
// the exact R6 swizzled layouts), saving the serial ~35-40us prep stage.
// Compute core (swapped QK^T, in-register softmax via cvt_pk+permlane, PV)
// is byte-identical to the verified R6 kernel.
__global__ __launch_bounds__(256, 4)
void continual_attn(const float* __restrict__ Qg, const float* __restrict__ Kf,
                    const float* __restrict__ Vf, const int* __restrict__ ATT,
                    float* __restrict__ OUT)
{
  // [key][64] / [d][64] rows of 128B; 16B slot s of row r holds logical chunk s^(r&7)
  __shared__ __align__(16) bf16_t Klds[2][KT * 64];   // 2 x 8 KB
  __shared__ __align__(16) bf16_t Vlds[2][Dc * KT];   // 2 x 8 KB  (total 32 KB)

  const int bid  = blockIdx.x;
  // heavy-first mapping (R6): test blocks then causal descending
  const int g    = bid >> 5;
  const int qblk = (g < 8) ? (24 + g) : (31 - g);
  const int h    = bid & 7;
  const int b    = (bid >> 3) & 3;
  const int q0   = qblk * ROWS_BLK;

  const int tid  = (int)threadIdx.x;
  const int wave = tid >> 6;
  const int lane = tid & 63;
  const int quad = lane >> 4;
  const int col  = lane & 15;
  const int qw   = q0 + wave * 16;

  const size_t bhQ = (size_t)b * Lc * HD + (size_t)h * Dc;

  // ---- staging assignments (fp32 sources) ----
  // K: thread covers row kr = tid>>2 of the tile, 16 floats at d0 = (tid&3)*16
  const float* ksrcF = Kf + bhQ + (size_t)(tid >> 2) * HD + (tid & 3) * 16;
  // V (transpose gather): thread covers output row d = tid&63, keys 16*(tid>>6)..+15
  const float* vsrcF = Vf + bhQ + (tid & 63);
  const int    vgk   = 16 * (tid >> 6);

  float kst[16], vst[16];          // staging registers (reused across phases)

  auto LOADT = [&](int k0v) {      // issue fp32 global loads of tile k0v
#pragma unroll
    for (int i = 0; i < 4; ++i)
      *(float4*)(kst + 4 * i) = *(const float4*)(ksrcF + (size_t)k0v * HD + 4 * i);
#pragma unroll
    for (int j = 0; j < 16; ++j)   // 16 coalesced 256B row-segments (lane = d)
      vst[j] = vsrcF[(size_t)(k0v + vgk + j) * HD];
  };

  auto mk8l = [](unsigned w0, unsigned w1, unsigned w2, unsigned w3) {
    union { unsigned u[4]; bf16x8 v; } x;
    x.u[0] = w0; x.u[1] = w1; x.u[2] = w2; x.u[3] = w3;
    return x.v;
  };

  auto CVTW = [&](int bi) {        // cast regs -> bf16, write R6-swizzled LDS
    unsigned kd[8], vd[8];
#pragma unroll
    for (int m = 0; m < 8; ++m) {
      asm("v_cvt_pk_bf16_f32 %0, %1, %2" : "=v"(kd[m]) : "v"(kst[2*m]), "v"(kst[2*m+1]));
      asm("v_cvt_pk_bf16_f32 %0, %1, %2" : "=v"(vd[m]) : "v"(vst[2*m]), "v"(vst[2*m+1]));
    }
    {
      const int r = tid >> 2, cb = 2 * (tid & 3);
      bf16_t* kt = Klds[bi] + r * 64;
      *(bf16x8*)(kt + (((cb    ) ^ (r & 7)) << 3)) = mk8l(kd[0], kd[1], kd[2], kd[3]);
      *(bf16x8*)(kt + (((cb + 1) ^ (r & 7)) << 3)) = mk8l(kd[4], kd[5], kd[6], kd[7]);
    }
    {
      const int d = tid & 63, g2 = 2 * (tid >> 6);
      bf16_t* vt = Vlds[bi] + d * 64;
      *(bf16x8*)(vt + (((g2    ) ^ (d & 7)) << 3)) = mk8l(vd[0], vd[1], vd[2], vd[3]);
      *(bf16x8*)(vt + (((g2 + 1) ^ (d & 7)) << 3)) = mk8l(vd[4], vd[5], vd[6], vd[7]);
    }
  };

  // ---- Q fragments (row=col, k=quad*8+j), prescaled by 1/8 * log2(e) ----
  bf16x8 aq[2];
  {
    const float* qp = Qg + bhQ + (size_t)(qw + col) * HD + quad * 8;
    const float SC = 0.125f * 1.44269504f;
#pragma unroll
    for (int t = 0; t < 2; ++t) {
      float4 lo = *(const float4*)(qp + t * 32);
      float4 hi = *(const float4*)(qp + t * 32 + 4);
      bf16x8 v;
      v[0] = (bf16_t)(lo.x * SC); v[1] = (bf16_t)(lo.y * SC);
      v[2] = (bf16_t)(lo.z * SC); v[3] = (bf16_t)(lo.w * SC);
      v[4] = (bf16_t)(hi.x * SC); v[5] = (bf16_t)(hi.y * SC);
      v[6] = (bf16_t)(hi.z * SC); v[7] = (bf16_t)(hi.w * SC);
      aq[t] = v;
    }
  }

  // ---- per-lane mask scalars (this lane's q-row is q = qw + col) ----
  const bool testblk = (q0 >= TRAINc);
  const int qi = qw + col;
  int kendL, cstartL;
  if (testblk) {
    kendL   = ATT[b * 64 + ((qi - TRAINc) >> 3)] + 1;
    cstartL = qi & ~7;
  } else {
    kendL   = qi + 1;
    cstartL = 0;
  }

  int ntA, ndiag, kfull_end;
  if (testblk) {
    int c0 = (q0 - TRAINc) >> 3;
    int amax = 0, amin = 0x7fffffff;
#pragma unroll
    for (int i = 0; i < 8; ++i) {
      int a = ATT[b * 64 + c0 + i];
      amax = (a > amax) ? a : amax;
      amin = (a < amin) ? a : amin;
    }
    ntA = (amax >> 6) + 1;   // 64-wide tiles covering [0, amax]
    ndiag = 1;               // own 64-wide diagonal block at k0=q0
    kfull_end = amin + 1;
  } else {
    ntA = qblk + 1;          // causal tiles covering [0, q0+64)
    ndiag = 0;
    kfull_end = q0 + 1;
  }
  const int ntot = ntA + ndiag;

  auto tk = [&](int t) { return (t < ntA) ? t * KT : q0 + (t - ntA) * KT; };

  float ls[4] = {0.f, 0.f, 0.f, 0.f};
  f32x4 o[4] = {{0,0,0,0},{0,0,0,0},{0,0,0,0},{0,0,0,0}};

  const int cA = ((quad ^ (col & 7)) << 3);   // swizzled 16B slot for k/d 0..31

  // ---- prologue: tile 0 -> buf0; issue loads of tile 1 ----
  LOADT(0);
  CVTW(0);                       // waits on the loads (data dep), writes buf0
  if (ntot > 1) LOADT(tk(1));
  __syncthreads();               // buf0 visible to all waves

  for (int ti = 0; ti < ntot; ++ti) {
    // cast+write NEXT tile from regs (loaded last phase), then refill regs
    if (ti + 1 < ntot) CVTW((ti + 1) & 1);
    if (ti + 2 < ntot) LOADT(tk(ti + 2));

    const bf16_t* kb   = Klds[ti & 1];
    const bf16_t* vbuf = Vlds[ti & 1];
    const int k0 = tk(ti);

    // ---- S^T = K Q^T  (swapped; sf[kg][r] = S[key=k0+kg*16+quad*4+r][q=qi]) ----
    f32x4 sf[4] = {{0,0,0,0},{0,0,0,0},{0,0,0,0},{0,0,0,0}};
    __builtin_amdgcn_s_setprio(1);
#pragma unroll
    for (int kg = 0; kg < 4; ++kg) {
      const bf16_t* krow = kb + (kg * 16 + col) * 64;
      bf16x8 k0f = *(const bf16x8*)(krow + cA);
      bf16x8 k1f = *(const bf16x8*)(krow + (cA ^ 32));
      sf[kg] = MFMA16(k0f, aq[0], sf[kg]);
      sf[kg] = MFMA16(k1f, aq[1], sf[kg]);
    }
    __builtin_amdgcn_s_setprio(0);

    const int mode = (ti >= ntA) ? 2 : ((k0 + KT <= kfull_end) ? 0 : 1);
    if (mode == 1) {
#pragma unroll
      for (int kg = 0; kg < 4; ++kg) {
        const int kv = k0 + kg * 16 + quad * 4;
#pragma unroll
        for (int r = 0; r < 4; ++r)
          if (kv + r >= kendL) sf[kg][r] = -1e30f;
      }
    } else if (mode == 2) {
#pragma unroll
      for (int kg = 0; kg < 4; ++kg) {
        const int kv = k0 + kg * 16 + quad * 4;
#pragma unroll
        for (int r = 0; r < 4; ++r)
          if (kv + r < cstartL || kv + r > qi) sf[kg][r] = -1e30f;
      }
    }

    // ---- exp2 (fixed-max: logits*log2e bounded, exp2 fp32/bf16-safe) ----
    float pvv[4][4];
#pragma unroll
    for (int kg = 0; kg < 4; ++kg)
#pragma unroll
      for (int r = 0; r < 4; ++r) {
        float p = __builtin_amdgcn_exp2f(sf[kg][r]);
        pvv[kg][r] = p;
        ls[r] += p;
      }

    // ---- pack to bf16 pairs + quad redistribution (in-register P transpose) ----
    unsigned Dw[4][2];
#pragma unroll
    for (int kg = 0; kg < 4; ++kg)
#pragma unroll
      for (int d = 0; d < 2; ++d)
        asm("v_cvt_pk_bf16_f32 %0, %1, %2"
            : "=v"(Dw[kg][d]) : "v"(pvv[kg][2 * d]), "v"(pvv[kg][2 * d + 1]));

    unsigned a0 = Dw[0][0], b0 = Dw[1][0];
    asm volatile("v_permlane32_swap_b32 %0, %1" : "+v"(a0), "+v"(b0));
    asm volatile("v_permlane16_swap_b32 %0, %1" : "+v"(a0), "+v"(b0));
    unsigned a1 = Dw[0][1], b1 = Dw[1][1];
    asm volatile("v_permlane32_swap_b32 %0, %1" : "+v"(a1), "+v"(b1));
    asm volatile("v_permlane16_swap_b32 %0, %1" : "+v"(a1), "+v"(b1));
    unsigned a2 = Dw[2][0], b2 = Dw[3][0];
    asm volatile("v_permlane32_swap_b32 %0, %1" : "+v"(a2), "+v"(b2));
    asm volatile("v_permlane16_swap_b32 %0, %1" : "+v"(a2), "+v"(b2));
    unsigned a3 = Dw[2][1], b3 = Dw[3][1];
    asm volatile("v_permlane32_swap_b32 %0, %1" : "+v"(a3), "+v"(b3));
    asm volatile("v_permlane16_swap_b32 %0, %1" : "+v"(a3), "+v"(b3));

    bf16x8 pa0 = mk8l(a0, a1, b0, b1);   // P[q=col][keys quad*8+0..7]
    bf16x8 pa1 = mk8l(a2, a3, b2, b3);   // P[q=col][keys 32+quad*8..+7]

    // ---- O += P V ----
    __builtin_amdgcn_s_setprio(1);
#pragma unroll
    for (int t = 0; t < 4; ++t) {
      const bf16_t* vrow = vbuf + (t * 16 + col) * 64;
      bf16x8 v0 = *(const bf16x8*)(vrow + cA);
      bf16x8 v1 = *(const bf16x8*)(vrow + (cA ^ 32));
      o[t] = MFMA16(pa0, v0, o[t]);
      o[t] = MFMA16(pa1, v1, o[t]);
    }
    __builtin_amdgcn_s_setprio(0);

    __syncthreads();   // writes(t+1) visible; frag reads(t) done before next overwrite
  }

  // ---- epilogue: denom per-lane; reduce over quads, normalize, store ----
  float rs = (ls[0] + ls[1]) + (ls[2] + ls[3]);
  rs += __shfl_xor(rs, 16);
  rs += __shfl_xor(rs, 32);
#pragma unroll
  for (int r = 0; r < 4; ++r) {
    float dr = __shfl(rs, quad * 4 + r);   // lane (quad*4+r) has denom for q=qw+quad*4+r
    float inv = 1.f / dr;
    int qo = qw + quad * 4 + r;
    float* op = OUT + ((size_t)b * Lc + qo) * HD + (size_t)h * Dc + col;
    op[0]  = o[0][r] * inv;
    op[16] = o[1][r] * inv;
    op[32] = o[2][r] * inv;
    op[48] = o[3][r] * inv;
  }
}

extern "C" void kernel_launch(void* const* d_in, const int* in_sizes, int n_in,
                              void* d_out, int out_size, void* d_ws, size_t ws_size,
                              hipStream_t stream) {
  const float* Q   = (const float*)d_in[0];
  const float* K   = (const float*)d_in[1];
  const float* V   = (const float*)d_in[2];
  const int*   ATT = (const int*)d_in[3];
  float* OUT = (float*)d_out;
  (void)in_sizes; (void)n_in; (void)out_size; (void)d_ws; (void)ws_size;

  continual_attn<<<dim3(Bc * Hc * (Lc / ROWS_BLK)), dim3(256), 0, stream>>>(Q, K, V, ATT, OUT);
}